// Round 8
// baseline (206.702 us; speedup 1.0000x reference)
//
#include <hip/hip_runtime.h>
#include <math.h>

// WL1 loss over [B=16, C=3, H=512, W=512] fp32.
//   r = sum_c|hr-sr|/255 ; e = sum_c|hr-ema|/255
//   patch_w[b] = (unbiased var of r over sample)^0.2
//   pixel_w = unbiased 3x3 local var of r (reflect pad)
//   loss = mean(|w*sr - w*hr|) = (1/N) sum patch_w * pixel_w * mask * 255*r
//
// R9: single-pass + streaming-shaped loads + fused final reduce.
//  - Main loop = 4 IDENTICAL guard-free iterations x 9 contiguous float4
//    loads (h,s,ema of one owned row): the exact shape that lifted R8-K1 to
//    >=3.4 TB/s. r -> LDS rt, e -> LDS ee, v1/v2 accumulated inline.
//  - Small tail: 2 halo rows (r only) + 36 halo columns.
//  - One __syncthreads (all loads already consumed -> drain free), then the
//    R1-verified 3x3 stencil with e read from LDS. No rfield round-trip.
//  - Final reduce fused via last-block-done atomic (counter cleared each
//    launch with hipMemsetAsync — graph-capture legal). One kernel total.

#define BB 16
#define HH 512
#define WW 512
#define HW (HH * WW)
#define CHW (3 * HW)
#define NT 1024          // 16 batches x 32 h-tiles x 2 w-halves (tile 16x256)
#define LDS_STRIDE 264   // col 3 = left halo, 4..259 = centers, 260 = right halo

__device__ __forceinline__ int reflect_h(int gh) {
  gh = gh < 0 ? -gh : gh;
  return gh >= HH ? 2 * HH - 2 - gh : gh;
}

__global__ __launch_bounds__(256) void wl1_fused(
    const float* __restrict__ sr, const float* __restrict__ srema,
    const float* __restrict__ hr,
    float* __restrict__ p_sum, float* __restrict__ p_sum2,
    float* __restrict__ p_loss, unsigned int* __restrict__ counter,
    float* __restrict__ out) {
  __shared__ float rt[18][LDS_STRIDE];  // r, rows h0-1 .. h0+16
  __shared__ float ee[16][256];         // e, owned rows
  const int bid = blockIdx.x;
  const int b = bid >> 6;
  const int t = bid & 63;
  const int h0 = (t >> 1) << 4;  // 0,16,...,496
  const int w0 = (t & 1) << 8;   // 0 or 256
  const int tid = threadIdx.x;
  const int c4 = tid & 63;       // float4 column group (0..63)
  const int rs = tid >> 6;       // wave id (0..3) -> uniform branches
  const float* __restrict__ srb = sr + (size_t)b * CHW;
  const float* __restrict__ hrb = hr + (size_t)b * CHW;
  const float* __restrict__ emb = srema + (size_t)b * CHW;

  float v1 = 0.f, v2 = 0.f, v3 = 0.f;

  // ---- main loop: 4 identical guard-free iterations, 9 f4 loads each ----
  // iteration k: owned row o = 4k + rs (gh = h0+o, always interior -> no
  // reflect, no branch). r -> rt[o+1], e -> ee[o], v1/v2 accumulate.
#pragma unroll
  for (int k = 0; k < 4; ++k) {
    const int o = 4 * k + rs;
    const int base = (h0 + o) * WW + w0 + 4 * c4;
    const float* hp = hrb + base;
    const float* sp = srb + base;
    const float* ep = emb + base;
    float4 h0v = *(const float4*)(hp);
    float4 h1v = *(const float4*)(hp + HW);
    float4 h2v = *(const float4*)(hp + 2 * HW);
    float4 s0v = *(const float4*)(sp);
    float4 s1v = *(const float4*)(sp + HW);
    float4 s2v = *(const float4*)(sp + 2 * HW);
    float4 e0v = *(const float4*)(ep);
    float4 e1v = *(const float4*)(ep + HW);
    float4 e2v = *(const float4*)(ep + 2 * HW);
    float4 r4;
    r4.x = (fabsf(h0v.x - s0v.x) + fabsf(h1v.x - s1v.x) + fabsf(h2v.x - s2v.x)) / 255.0f;
    r4.y = (fabsf(h0v.y - s0v.y) + fabsf(h1v.y - s1v.y) + fabsf(h2v.y - s2v.y)) / 255.0f;
    r4.z = (fabsf(h0v.z - s0v.z) + fabsf(h1v.z - s1v.z) + fabsf(h2v.z - s2v.z)) / 255.0f;
    r4.w = (fabsf(h0v.w - s0v.w) + fabsf(h1v.w - s1v.w) + fabsf(h2v.w - s2v.w)) / 255.0f;
    float4 e4;
    e4.x = (fabsf(h0v.x - e0v.x) + fabsf(h1v.x - e1v.x) + fabsf(h2v.x - e2v.x)) / 255.0f;
    e4.y = (fabsf(h0v.y - e0v.y) + fabsf(h1v.y - e1v.y) + fabsf(h2v.y - e2v.y)) / 255.0f;
    e4.z = (fabsf(h0v.z - e0v.z) + fabsf(h1v.z - e1v.z) + fabsf(h2v.z - e2v.z)) / 255.0f;
    e4.w = (fabsf(h0v.w - e0v.w) + fabsf(h1v.w - e1v.w) + fabsf(h2v.w - e2v.w)) / 255.0f;
    *(float4*)&rt[o + 1][4 + 4 * c4] = r4;
    *(float4*)&ee[o][4 * c4] = e4;
    v1 += r4.x + r4.y + r4.z + r4.w;
    v2 += r4.x * r4.x + r4.y * r4.y + r4.z * r4.z + r4.w * r4.w;
  }

  // ---- tail: halo rows (rt rows 0 and 17), r only ----
  if (tid < 128) {
    const int row = (tid >> 6) * 17;  // 0 or 17
    const int gh = reflect_h(h0 - 1 + row);
    const int base = gh * WW + w0 + 4 * (tid & 63);
    const float* hp = hrb + base;
    const float* sp = srb + base;
    float4 h0v = *(const float4*)(hp);
    float4 h1v = *(const float4*)(hp + HW);
    float4 h2v = *(const float4*)(hp + 2 * HW);
    float4 s0v = *(const float4*)(sp);
    float4 s1v = *(const float4*)(sp + HW);
    float4 s2v = *(const float4*)(sp + 2 * HW);
    float4 r4;
    r4.x = (fabsf(h0v.x - s0v.x) + fabsf(h1v.x - s1v.x) + fabsf(h2v.x - s2v.x)) / 255.0f;
    r4.y = (fabsf(h0v.y - s0v.y) + fabsf(h1v.y - s1v.y) + fabsf(h2v.y - s2v.y)) / 255.0f;
    r4.z = (fabsf(h0v.z - s0v.z) + fabsf(h1v.z - s1v.z) + fabsf(h2v.z - s2v.z)) / 255.0f;
    r4.w = (fabsf(h0v.w - s0v.w) + fabsf(h1v.w - s1v.w) + fabsf(h2v.w - s2v.w)) / 255.0f;
    *(float4*)&rt[row][4 + 4 * (tid & 63)] = r4;
  } else if (tid < 164) {
    // ---- tail: 36 halo-column items (rows 0..17, left/right) ----
    const int ht = tid - 128;
    const int row = ht >> 1, side = ht & 1;
    const int gh = reflect_h(h0 - 1 + row);
    int gw = side ? w0 + 256 : w0 - 1;
    if (gw < 0) gw = 1;
    if (gw > 511) gw = 1022 - gw;
    const int base = gh * WW + gw;
    float v = (fabsf(hrb[base] - srb[base]) +
               fabsf(hrb[base + HW] - srb[base + HW]) +
               fabsf(hrb[base + 2 * HW] - srb[base + 2 * HW])) /
              255.0f;
    rt[row][side ? 260 : 3] = v;
  }
  __syncthreads();

  // ---- stencil: 4 rows x 4 cols per thread, pure LDS+VALU (R1-verified) ----
#pragma unroll
  for (int rr = 0; rr < 4; ++rr) {
    const int o = 4 * rr + rs;  // output row, LDS center row = o+1
    float cs[6] = {0, 0, 0, 0, 0, 0}, cq[6] = {0, 0, 0, 0, 0, 0};
    float center[4];
#pragma unroll
    for (int dr = 0; dr < 3; ++dr) {
      const float* lp = &rt[o + dr][4 * c4];
      float4 a = *(const float4*)(lp);
      float4 bq = *(const float4*)(lp + 4);
      float4 cq4 = *(const float4*)(lp + 8);
      float f3 = a.w, f4 = bq.x, f5 = bq.y, f6 = bq.z, f7 = bq.w, f8 = cq4.x;
      cs[0] += f3; cq[0] += f3 * f3;
      cs[1] += f4; cq[1] += f4 * f4;
      cs[2] += f5; cq[2] += f5 * f5;
      cs[3] += f6; cq[3] += f6 * f6;
      cs[4] += f7; cq[4] += f7 * f7;
      cs[5] += f8; cq[5] += f8 * f8;
      if (dr == 1) { center[0] = f4; center[1] = f5; center[2] = f6; center[3] = f7; }
    }
    const float4 e4 = *(const float4*)&ee[o][4 * c4];
    const float ev[4] = {e4.x, e4.y, e4.z, e4.w};
#pragma unroll
    for (int cc = 0; cc < 4; ++cc) {
      float s = cs[cc] + cs[cc + 1] + cs[cc + 2];
      float q = cq[cc] + cq[cc + 1] + cq[cc + 2];
      float pvar = (q - s * s / 9.0f) / 8.0f;
      float rc = center[cc];
      if (rc >= ev[cc]) v3 += pvar * (255.0f * rc);
    }
  }

  // ---- block reduce (4 waves) ----
#pragma unroll
  for (int off = 32; off > 0; off >>= 1) {
    v1 += __shfl_down(v1, off, 64);
    v2 += __shfl_down(v2, off, 64);
    v3 += __shfl_down(v3, off, 64);
  }
  __shared__ float red[3][4];
  if (c4 == 0) {
    red[0][rs] = v1;
    red[1][rs] = v2;
    red[2][rs] = v3;
  }
  __syncthreads();
  __shared__ int is_last;
  if (tid == 0) {
    p_sum[bid] = red[0][0] + red[0][1] + red[0][2] + red[0][3];
    p_sum2[bid] = red[1][0] + red[1][1] + red[1][2] + red[1][3];
    p_loss[bid] = red[2][0] + red[2][1] + red[2][2] + red[2][3];
    __threadfence();
    unsigned int prev = atomicAdd(counter, 1u);
    is_last = (prev == NT - 1) ? 1 : 0;
  }
  __syncthreads();
  if (is_last == 0) return;

  // ---- last block: final reduce over 1024 partials ----
  __threadfence();
  double s = 0.0, s2 = 0.0, sl = 0.0;
#pragma unroll
  for (int j = 0; j < 4; ++j) {
    const int i = tid + 256 * j;
    s += (double)p_sum[i];
    s2 += (double)p_sum2[i];
    sl += (double)p_loss[i];
  }
  // per-batch grouping: partial i belongs to batch i>>6. Reduce per-batch
  // sums via LDS (need per-batch var, not global). Each batch = 64 partials.
  __shared__ double bs[BB], bs2[BB], bsl[BB];
  if (tid < BB) { bs[tid] = 0.0; bs2[tid] = 0.0; bsl[tid] = 0.0; }
  __syncthreads();
  // thread handles partials {tid, tid+256, tid+512, tid+768}; those span 4
  // different batches (i>>6 = tid>>6 + 4j). Accumulate per element instead.
  // Redo with explicit per-batch accumulation (simpler, still fast):
  if (tid < 64) {
    // thread k of first wave group: batch = k>>2, entries 16*(k&3)..+15
    // Simpler exact scheme: 64 threads, thread k sums batch k>>2's quarter.
  }
  // --- straightforward exact reduction: one wave per 4 batches ---
  if (tid < 128) {
    const int bb = tid >> 3;        // batch 0..15
    const int kk = tid & 7;         // 8 threads per batch
    double ls = 0.0, ls2 = 0.0, lsl = 0.0;
#pragma unroll
    for (int j = 0; j < 8; ++j) {
      const int i = (bb << 6) + (kk << 3) + j;
      ls += (double)p_sum[i];
      ls2 += (double)p_sum2[i];
      lsl += (double)p_loss[i];
    }
    // reduce the 8 threads of this batch (they are contiguous lanes)
#pragma unroll
    for (int off = 4; off > 0; off >>= 1) {
      ls += __shfl_down(ls, off, 64);
      ls2 += __shfl_down(ls2, off, 64);
      lsl += __shfl_down(lsl, off, 64);
    }
    if (kk == 0) {
      const double n = (double)HW;
      double var = (ls2 - ls * ls / n) / (n - 1.0);
      bs[bb] = pow(var, 0.2) * lsl;
    }
  }
  __syncthreads();
  if (tid == 0) {
    double tot = 0.0;
#pragma unroll
    for (int j = 0; j < BB; ++j) tot += bs[j];
    out[0] = (float)(tot / (double)((size_t)BB * CHW));
  }
}

extern "C" void kernel_launch(void* const* d_in, const int* in_sizes, int n_in,
                              void* d_out, int out_size, void* d_ws,
                              size_t ws_size, hipStream_t stream) {
  const float* sr = (const float*)d_in[0];
  const float* srema = (const float*)d_in[1];
  const float* hr = (const float*)d_in[2];
  float* out = (float*)d_out;

  float* p_sum = (float*)d_ws;              // [1024]
  float* p_sum2 = p_sum + NT;               // [1024]
  float* p_loss = p_sum2 + NT;              // [1024]
  unsigned int* counter = (unsigned int*)(p_loss + NT);

  hipMemsetAsync(counter, 0, sizeof(unsigned int), stream);
  wl1_fused<<<NT, 256, 0, stream>>>(sr, srema, hr, p_sum, p_sum2, p_loss,
                                    counter, out);
}

// Round 9
// 162.928 us; speedup vs baseline: 1.2687x; 1.2687x over previous
//
#include <hip/hip_runtime.h>
#include <math.h>

// WL1 loss over [B=16, C=3, H=512, W=512] fp32.
//   r = sum_c|hr-sr|/255 ; e = sum_c|hr-ema|/255
//   patch_w[b] = (unbiased var of r over sample)^0.2
//   pixel_w = unbiased 3x3 local var of r (reflect pad)
//   loss = mean(|w*sr - w*hr|) = (1/N) sum patch_w * pixel_w * mask * 255*r
//
// R10: proven 3-kernel pipeline, optimized ends.
//  K1 wl1_stream (R8, unchanged): grid-stride guard-free streaming, 9 ntl
//     float4 loads/iter, sign-encoded m=(r>=e)?r:-r to 16.8MB ws field,
//     v1/v2 partials. Measured >=4.2 TB/s (under the 40.6us poison fill).
//  K2 wl1_var: R1's verified 16x256 tile geometry on the m-field (halo
//     12.5% instead of R8's 25%), v3 partials only.
//  K3 wl1_final: separate tiny reduce. R9 proved per-block threadfence
//     fusion costs ~60us (8-XCD L2 writeback) - never fuse via fence.

#define BB 16
#define HH 512
#define WW 512
#define HW (HH * WW)
#define CHW (3 * HW)

#define NB1 1024   // K1: 64 blocks/batch, 4 iters/thread
#define NB2 1024   // K2: tile 16x256, 64 blocks/batch
#define LDS_STRIDE 264  // col 3 = left halo, 4..259 = centers, 260 = right halo

typedef float f4v __attribute__((ext_vector_type(4)));

__device__ __forceinline__ f4v ntl(const float* p) {
  return __builtin_nontemporal_load((const f4v*)p);
}
__device__ __forceinline__ f4v absv(f4v a) {
  f4v r;
  r.x = fabsf(a.x); r.y = fabsf(a.y); r.z = fabsf(a.z); r.w = fabsf(a.w);
  return r;
}

__device__ __forceinline__ int reflect_h(int gh) {
  gh = gh < 0 ? -gh : gh;
  return gh >= HH ? 2 * HH - 2 - gh : gh;
}

// K1: streaming pass. Block bid -> batch b = bid>>6, 64 blocks/batch.
// Thread handles 4 quads (16 px) at stride 16384 quads within the batch plane.
__global__ __launch_bounds__(256) void wl1_stream(
    const float* __restrict__ sr, const float* __restrict__ srema,
    const float* __restrict__ hr, float* __restrict__ rfield,
    float* __restrict__ p_sum, float* __restrict__ p_sum2) {
  const int tid = threadIdx.x;
  const int bid = blockIdx.x;
  const int b = bid >> 6;                   // batch
  const int tq0 = ((bid & 63) << 8) | tid;  // base quad in plane (0..16383)
  const float* __restrict__ hb = hr + (size_t)b * CHW;
  const float* __restrict__ sb = sr + (size_t)b * CHW;
  const float* __restrict__ mb = srema + (size_t)b * CHW;
  float* __restrict__ rfb = rfield + ((size_t)b << 18);

  float v1 = 0.f, v2 = 0.f;
#pragma unroll
  for (int it = 0; it < 4; ++it) {
    const int qi = tq0 + (it << 14);  // quad index in plane (0..65535)
    const size_t off = (size_t)qi << 2;
    const float* hp = hb + off;
    const float* sp = sb + off;
    const float* ep = mb + off;
    f4v h0 = ntl(hp), h1 = ntl(hp + HW), h2 = ntl(hp + 2 * HW);
    f4v s0 = ntl(sp), s1 = ntl(sp + HW), s2 = ntl(sp + 2 * HW);
    f4v e0 = ntl(ep), e1 = ntl(ep + HW), e2 = ntl(ep + 2 * HW);

    f4v r4 = (absv(h0 - s0) + absv(h1 - s1) + absv(h2 - s2)) * (1.0f / 255.0f);
    f4v e4 = (absv(h0 - e0) + absv(h1 - e1) + absv(h2 - e2)) * (1.0f / 255.0f);

    // sign-encode mask: m = (r >= e) ? r : -r  (r contributes 0 when r==0)
    f4v m4;
    m4.x = (r4.x >= e4.x) ? r4.x : -r4.x;
    m4.y = (r4.y >= e4.y) ? r4.y : -r4.y;
    m4.z = (r4.z >= e4.z) ? r4.z : -r4.z;
    m4.w = (r4.w >= e4.w) ? r4.w : -r4.w;
    *(f4v*)(rfb + off) = m4;  // cached store; K2 re-reads it

    v1 += r4.x + r4.y + r4.z + r4.w;
    v2 += r4.x * r4.x + r4.y * r4.y + r4.z * r4.z + r4.w * r4.w;
  }

#pragma unroll
  for (int off = 32; off > 0; off >>= 1) {
    v1 += __shfl_down(v1, off, 64);
    v2 += __shfl_down(v2, off, 64);
  }
  __shared__ float red[2][4];
  const int wv = tid >> 6;
  if ((tid & 63) == 0) {
    red[0][wv] = v1;
    red[1][wv] = v2;
  }
  __syncthreads();
  if (tid == 0) {
    p_sum[bid] = red[0][0] + red[0][1] + red[0][2] + red[0][3];
    p_sum2[bid] = red[1][0] + red[1][1] + red[1][2] + red[1][3];
  }
}

// K2: 3x3 unbiased local var over |m|, masked by sign(m), 16x256 tiles.
__global__ __launch_bounds__(256) void wl1_var(
    const float* __restrict__ rfield, float* __restrict__ p_loss) {
  __shared__ float rt[18][LDS_STRIDE];
  const int bid = blockIdx.x;
  const int b = bid >> 6;
  const int t = bid & 63;
  const int h0 = (t >> 1) << 4;  // 0,16,...,496
  const int w0 = (t & 1) << 8;   // 0 or 256
  const int tid = threadIdx.x;
  const int c4 = tid & 63;
  const int rs = tid >> 6;  // wave id -> uniform branches
  const float* __restrict__ rb = rfield + ((size_t)b << 18);

  // Stage A: halo rows 0..17 -> LDS (raw, sign preserved)
#pragma unroll
  for (int it = 0; it < 5; ++it) {
    int row = it * 4 + rs;
    if (row < 18) {
      int gh = reflect_h(h0 - 1 + row);
      float4 v = *(const float4*)(rb + gh * WW + w0 + 4 * c4);
      *(float4*)&rt[row][4 + 4 * c4] = v;
    }
  }
  // halo columns (36 scalar items)
  if (tid < 36) {
    int row = tid >> 1, side = tid & 1;
    int gh = reflect_h(h0 - 1 + row);
    int gw = side ? w0 + 256 : w0 - 1;
    if (gw < 0) gw = 1;
    if (gw > 511) gw = 1022 - gw;
    rt[row][side ? 260 : 3] = rb[gh * WW + gw];
  }
  __syncthreads();

  // Stage B: 4 rows x 4 cols per thread, pure LDS+VALU
  float v3 = 0.f;
#pragma unroll
  for (int rr = 0; rr < 4; ++rr) {
    const int o = rr * 4 + rs;  // output row, LDS center row = o+1
    float cs[6] = {0, 0, 0, 0, 0, 0}, cq[6] = {0, 0, 0, 0, 0, 0};
    float craw[4];
#pragma unroll
    for (int dr = 0; dr < 3; ++dr) {
      const float* lp = &rt[o + dr][4 * c4];
      float4 a = *(const float4*)(lp);
      float4 bq = *(const float4*)(lp + 4);
      float4 cq4 = *(const float4*)(lp + 8);
      float f3 = fabsf(a.w), f4 = fabsf(bq.x), f5 = fabsf(bq.y),
            f6 = fabsf(bq.z), f7 = fabsf(bq.w), f8 = fabsf(cq4.x);
      cs[0] += f3; cq[0] += f3 * f3;
      cs[1] += f4; cq[1] += f4 * f4;
      cs[2] += f5; cq[2] += f5 * f5;
      cs[3] += f6; cq[3] += f6 * f6;
      cs[4] += f7; cq[4] += f7 * f7;
      cs[5] += f8; cq[5] += f8 * f8;
      if (dr == 1) { craw[0] = bq.x; craw[1] = bq.y; craw[2] = bq.z; craw[3] = bq.w; }
    }
#pragma unroll
    for (int cc = 0; cc < 4; ++cc) {
      float s = cs[cc] + cs[cc + 1] + cs[cc + 2];
      float q = cq[cc] + cq[cc + 1] + cq[cc + 2];
      float pvar = (q - s * s / 9.0f) / 8.0f;
      float raw = craw[cc];
      float rc = fabsf(raw);
      if (raw >= 0.0f) v3 += pvar * (255.0f * rc);  // sign<0 => masked out
    }
  }

#pragma unroll
  for (int off = 32; off > 0; off >>= 1) v3 += __shfl_down(v3, off, 64);
  __shared__ float red[4];
  if (c4 == 0) red[rs] = v3;
  __syncthreads();
  if (tid == 0) p_loss[bid] = red[0] + red[1] + red[2] + red[3];
}

// K3: final reduce — wave b handles batch b (64 partials of each kind).
__global__ __launch_bounds__(1024) void wl1_final(
    const float* __restrict__ p_sum, const float* __restrict__ p_sum2,
    const float* __restrict__ p_loss, float* __restrict__ out) {
  const int tid = threadIdx.x;
  const int b = tid >> 6, k = tid & 63;
  const int i = b * 64 + k;
  double s = (double)p_sum[i];
  double s2 = (double)p_sum2[i];
  double sl = (double)p_loss[i];
#pragma unroll
  for (int off = 32; off > 0; off >>= 1) {
    s += __shfl_down(s, off, 64);
    s2 += __shfl_down(s2, off, 64);
    sl += __shfl_down(sl, off, 64);
  }
  __shared__ double acc[BB];
  if (k == 0) {
    const double n = (double)HW;
    double var = (s2 - s * s / n) / (n - 1.0);
    acc[b] = pow(var, 0.2) * sl;
  }
  __syncthreads();
  if (tid == 0) {
    double tot = 0.0;
#pragma unroll
    for (int j = 0; j < BB; ++j) tot += acc[j];
    out[0] = (float)(tot / (double)((size_t)BB * CHW));
  }
}

extern "C" void kernel_launch(void* const* d_in, const int* in_sizes, int n_in,
                              void* d_out, int out_size, void* d_ws,
                              size_t ws_size, hipStream_t stream) {
  const float* sr = (const float*)d_in[0];
  const float* srema = (const float*)d_in[1];
  const float* hr = (const float*)d_in[2];
  float* out = (float*)d_out;

  float* p_sum = (float*)d_ws;   // [1024]
  float* p_sum2 = p_sum + NB1;   // [1024]
  float* p_loss = p_sum2 + NB1;  // [1024]
  float* rfield = p_loss + NB2;  // [16*512*512] = 16 MB, 16B-aligned

  wl1_stream<<<NB1, 256, 0, stream>>>(sr, srema, hr, rfield, p_sum, p_sum2);
  wl1_var<<<NB2, 256, 0, stream>>>(rfield, p_loss);
  wl1_final<<<1, 1024, 0, stream>>>(p_sum, p_sum2, p_loss, out);
}